// Round 18
// baseline (919.798 us; speedup 1.0000x reference)
//
#include <hip/hip_runtime.h>
#include <math.h>

#define E_DIM 1024
#define D_DIM 1024
#define A_DIM 512
#define B_NUM 32
#define S_DIM 2048
#define M_DIM (B_NUM * S_DIM)  // 65536

typedef unsigned short ushort;
typedef short short8 __attribute__((ext_vector_type(8)));
typedef float f32x4 __attribute__((ext_vector_type(4)));
typedef unsigned short ushort4v __attribute__((ext_vector_type(4)));
typedef unsigned int uint2v __attribute__((ext_vector_type(2)));

typedef const void __attribute__((address_space(1))) cglobal_t;
typedef void __attribute__((address_space(3))) lds_t;

__device__ __forceinline__ void gload_lds16(const void* g, void* l) {
    __builtin_amdgcn_global_load_lds((cglobal_t*)g, (lds_t*)l, 16, 0, 0);
}

__device__ __forceinline__ ushort f2bf(float x) {
    unsigned u = __float_as_uint(x);
    u += 0x7FFF + ((u >> 16) & 1);  // round-to-nearest-even
    return (ushort)(u >> 16);
}

__device__ __forceinline__ unsigned cvt_pk_bf16(float lo, float hi) {
    unsigned r;
    asm("v_cvt_pk_bf16_f32 %0, %1, %2" : "=v"(r) : "v"(lo), "v"(hi));
    return r;
}

__device__ __forceinline__ float fast_tanh(float x) {
    const float e = __expf(2.0f * x);
    return 1.0f - 2.0f * __builtin_amdgcn_rcpf(e + 1.0f);
}

// ---------------- K0: dec2[b][a] = dot(dh[b,:], Wd[:,a]) + bd[a] + be[a] ----------------
__global__ __launch_bounds__(256) void k0_dec_energy(
    const float* __restrict__ dh, const float* __restrict__ Wd,
    const float* __restrict__ bd, const float* __restrict__ be,
    float* __restrict__ dec2) {
    __shared__ float sdh[D_DIM];
    const int b = blockIdx.y;
    const int t = threadIdx.x;
    for (int i = t; i < D_DIM; i += 256) sdh[i] = dh[b * D_DIM + i];
    __syncthreads();
    const int a = blockIdx.x * 256 + t;
    float acc = bd[a] + be[a];
#pragma unroll 8
    for (int e = 0; e < D_DIM; ++e) acc += sdh[e] * Wd[(size_t)e * A_DIM + a];
    dec2[b * A_DIM + a] = acc;
}

// ---------------- K0b: Wt[a][e] = bf16(We[e][a]) ----------------
__global__ __launch_bounds__(256) void k0b_cvt_we(
    const float* __restrict__ We, ushort* __restrict__ Wt) {
    const int n = blockIdx.x;
    const int k0 = threadIdx.x * 4;
    ushort4v v;
#pragma unroll
    for (int j = 0; j < 4; ++j) v[j] = f2bf(We[(size_t)(k0 + j) * A_DIM + n]);
    *reinterpret_cast<ushort4v*>(&Wt[(size_t)n * E_DIM + k0]) = v;
}

// ---------------- K1: fused fp32->bf16 A-staging MFMA GEMM, coalesced A-loads ----------------
// 128x256 tile, 4 waves (64x128 each), BK=32, double-buffered 48KB LDS, 3 blocks/CU.
#define BM4 128
#define BN4 256
#define NT4 32
#define BUFU4 12288  // ushorts per buffer: A 4096 (8KB) + B 8192 (16KB)

__global__ __launch_bounds__(256, 3) void k1_fused(
    const float* __restrict__ enc, const ushort* __restrict__ Wt,
    const float* __restrict__ dec2, const float* __restrict__ v_w,
    float* __restrict__ pscores) {
    __shared__ ushort L[2 * BUFU4];  // 48KB

    const int t = threadIdx.x;
    const int l = t & 63;
    const int w = t >> 6;            // 0..3
    const int wm = w >> 1, wn = w & 1;  // 2x2 wave grid; wave-tile 64x128
    const int fr = l & 15;
    const int kg = l >> 4;

    // XCD swizzle: nwg=1024 (div 8); ny-pairs adjacent (share A-tile in L2)
    const int o = ((blockIdx.x & 7) << 7) | (blockIdx.x >> 3);
    const int x = o >> 1, ny = o & 1;
    const int row0 = x * BM4;
    const int n0 = ny * BN4;
    const int b = row0 >> 11;

    // ---- A staging: COALESCED lane map. instr q: row=q*32+(t>>3), chunk=t&7 (float4).
    const int arow = t >> 3;         // 0..31 (+ q*32)
    const int achk = t & 7;          // 16B chunk within 128B k-row
    const float* AsrcT = enc + (size_t)(row0 + arow) * E_DIM + achk * 4;
    const int aswzc = ((((achk >> 1) ^ ((t >> 4) & 3)) << 4) | ((t & 1) << 3));
    const int awbase = arow * 64 + aswzc;  // + q*2048 bytes

    // ---- B staging (pre-swizzled global source -> gload_lds, linear dest) ----
    const ushort* BsrcQ[4];
#pragma unroll
    for (int q = 0; q < 4; ++q) {
        const int row = q * 64 + w * 16 + (l >> 2);
        const int c = (l & 3) ^ ((row >> 1) & 3);
        BsrcQ[q] = Wt + (size_t)(n0 + row) * E_DIM + c * 8;
    }

    f32x4 acc[4][8];
#pragma unroll
    for (int i = 0; i < 4; ++i)
#pragma unroll
        for (int j = 0; j < 8; ++j) acc[i][j] = (f32x4){0.f, 0.f, 0.f, 0.f};

    float4 paA[4], paB[4];

#define LOADA4(pa, ktv)                                                        \
    {                                                                          \
        _Pragma("unroll") for (int q = 0; q < 4; ++q)                          \
            pa[q] = *reinterpret_cast<const float4*>(                          \
                AsrcT + (size_t)q * 32 * E_DIM + (ktv) * 32);                  \
    }

#define STAGEB4(cb, ktv)                                                       \
    {                                                                          \
        _Pragma("unroll") for (int q = 0; q < 4; ++q)                          \
            gload_lds16(BsrcQ[q] + (ktv) * 32,                                 \
                        L + (cb) * BUFU4 + 4096 + (q * 64 + w * 16) * 32);     \
    }

#define WRITEA4(cb, pa)                                                        \
    {                                                                          \
        _Pragma("unroll") for (int q = 0; q < 4; ++q) {                        \
            uint2v v2;                                                         \
            v2[0] = cvt_pk_bf16(pa[q].x, pa[q].y);                             \
            v2[1] = cvt_pk_bf16(pa[q].z, pa[q].w);                             \
            *reinterpret_cast<uint2v*>(                                        \
                (char*)L + (cb) * 24576 + q * 2048 + awbase) = v2;             \
        }                                                                      \
    }

#define MFMA_BLOCK(cur)                                                        \
    {                                                                          \
        const char* Ab = (const char*)L + (cur) * 24576;                       \
        const char* Bb = Ab + 8192;                                            \
        short8 af[4], bf[8];                                                   \
        _Pragma("unroll") for (int i = 0; i < 4; ++i) {                        \
            const int r = wm * 64 + i * 16 + fr;                               \
            af[i] = *reinterpret_cast<const short8*>(                          \
                Ab + r * 64 + ((kg ^ ((r >> 1) & 3)) << 4));                   \
        }                                                                      \
        _Pragma("unroll") for (int j = 0; j < 8; ++j) {                        \
            const int r = wn * 128 + j * 16 + fr;                              \
            bf[j] = *reinterpret_cast<const short8*>(                          \
                Bb + r * 64 + ((kg ^ ((r >> 1) & 3)) << 4));                   \
        }                                                                      \
        __builtin_amdgcn_s_setprio(1);                                         \
        _Pragma("unroll") for (int i = 0; i < 4; ++i)                          \
            _Pragma("unroll") for (int j = 0; j < 8; ++j)                      \
                acc[i][j] = __builtin_amdgcn_mfma_f32_16x16x32_bf16(           \
                    af[i], bf[j], acc[i][j], 0, 0, 0);                         \
        __builtin_amdgcn_s_setprio(0);                                         \
    }

#define WAITV(n) asm volatile("s_waitcnt vmcnt(" #n ")" ::: "memory")
#define WAITLG() asm volatile("s_waitcnt lgkmcnt(0)" ::: "memory")
#define BARRIER() __builtin_amdgcn_s_barrier()

    // ---- prologue: A(0), B(0), A(1); write A(0); wait B(0); barrier ----
    LOADA4(paA, 0);
    STAGEB4(0, 0);
    LOADA4(paB, 1);
    WAITV(8);           // A(0) regs landed
    WRITEA4(0, paA);
    WAITV(4);           // B(0) DMA landed; A(1) in flight
    WAITLG();
    BARRIER();

    // ---- main loop: steady-state 12 outstanding, counted waits, depth-2 A ----
#define ITER(kt, paW, paL)                                                     \
    {                                                                          \
        const int cur = (kt) & 1;                                              \
        STAGEB4(cur ^ 1, (kt) + 1);  /* +4: B(kt+1) */                         \
        LOADA4(paL, (kt) + 2);       /* +4: A(kt+2) */                         \
        MFMA_BLOCK(cur);                                                       \
        WAITV(8);                    /* retire A(kt+1) regs (paW) */           \
        WRITEA4(cur ^ 1, paW);                                                 \
        WAITV(4);                    /* retire B(kt+1); A(kt+2) in flight */   \
        WAITLG();                                                              \
        BARRIER();                                                             \
    }

    for (int kp = 0; kp < 30; kp += 2) {
        ITER(kp, paB, paA);      // writes A(kt+1)=paB, loads A(kt+2)->paA
        ITER(kp + 1, paA, paB);  // writes A(kt+1)=paA, loads A(kt+2)->paB
    }
    // kt = 30: stage B(31); no more A-loads; write A(31)=paB
    {
        STAGEB4(1, 31);
        MFMA_BLOCK(0);
        WAITV(4);            // retire A(31) regs (4 oldest of 8)
        WRITEA4(1, paB);
        WAITV(0);            // B(31) landed
        WAITLG();
        BARRIER();
    }
    // kt = 31: compute only
    MFMA_BLOCK(1);

    // ---- epilogue: rowsum = sum over wave's 128 cols of tanh(acc+dec2)*v_w ----
    float rowsum[4][4];
#pragma unroll
    for (int i = 0; i < 4; ++i)
#pragma unroll
        for (int r = 0; r < 4; ++r) rowsum[i][r] = 0.0f;

#pragma unroll
    for (int j = 0; j < 8; ++j) {
        const int ag = n0 + wn * 128 + j * 16 + fr;
        const float bias = dec2[b * A_DIM + ag];
        const float vw = v_w[ag];
#pragma unroll
        for (int i = 0; i < 4; ++i)
#pragma unroll
            for (int r = 0; r < 4; ++r)
                rowsum[i][r] += fast_tanh(acc[i][j][r] + bias) * vw;
    }
#pragma unroll
    for (int m = 1; m < 16; m <<= 1)
#pragma unroll
        for (int i = 0; i < 4; ++i)
#pragma unroll
            for (int r = 0; r < 4; ++r)
                rowsum[i][r] += __shfl_xor(rowsum[i][r], m, 64);

    __syncthreads();
    float* red = reinterpret_cast<float*>(L);  // [128][2]
    if (fr == 0) {
#pragma unroll
        for (int i = 0; i < 4; ++i)
#pragma unroll
            for (int r = 0; r < 4; ++r)
                red[(wm * 64 + i * 16 + kg * 4 + r) * 2 + wn] = rowsum[i][r];
    }
    __syncthreads();
    if (t < BM4)
        pscores[(size_t)(row0 + t) * 2 + ny] = red[t * 2] + red[t * 2 + 1];
}

// ---------------- K2: softmax over S per batch (W column partials) ----------------
__global__ __launch_bounds__(256) void k2_softmax(
    const float* __restrict__ pscores, const float* __restrict__ v_b,
    float* __restrict__ attn_out, int W) {
    __shared__ float sc[S_DIM];
    __shared__ float red[8];
    const int b = blockIdx.x;
    const int t = threadIdx.x;
    const int wave = t >> 6, lane = t & 63;
    const float vb = v_b[0];

    float lmax = -1e30f;
    for (int s = t; s < S_DIM; s += 256) {
        float v = vb;
        for (int c = 0; c < W; ++c) v += pscores[(size_t)(b * S_DIM + s) * W + c];
        sc[s] = v;
        lmax = fmaxf(lmax, v);
    }
#pragma unroll
    for (int off = 32; off > 0; off >>= 1) lmax = fmaxf(lmax, __shfl_down(lmax, off, 64));
    if (lane == 0) red[wave] = lmax;
    __syncthreads();
    const float bmax = fmaxf(fmaxf(red[0], red[1]), fmaxf(red[2], red[3]));

    float lsum = 0.0f;
    for (int s = t; s < S_DIM; s += 256) {
        const float e = expf(sc[s] - bmax);
        sc[s] = e;
        lsum += e;
    }
#pragma unroll
    for (int off = 32; off > 0; off >>= 1) lsum += __shfl_down(lsum, off, 64);
    if (lane == 0) red[4 + wave] = lsum;
    __syncthreads();
    const float inv = 1.0f / (red[4] + red[5] + red[6] + red[7]);
    for (int s = t; s < S_DIM; s += 256) attn_out[b * S_DIM + s] = sc[s] * inv;
}

// ---------------- K3: context partials (fp32 enc; L3-resident after K1) ----------------
#define SC_CHUNK 128
#define N_SC (S_DIM / SC_CHUNK)  // 16
__global__ __launch_bounds__(256) void k3_ctx_partial(
    const float* __restrict__ enc, const float* __restrict__ attn,
    float* __restrict__ pctx) {
    const int b = blockIdx.y;
    const int scb = blockIdx.x;
    const int t = threadIdx.x;
    const int s0 = scb * SC_CHUNK;
    float4 acc = {0.0f, 0.0f, 0.0f, 0.0f};
    const float4* encv =
        reinterpret_cast<const float4*>(enc + (size_t)(b * S_DIM + s0) * E_DIM);
#pragma unroll 4
    for (int s = 0; s < SC_CHUNK; ++s) {
        const float w = attn[b * S_DIM + s0 + s];
        const float4 v = encv[(size_t)s * (E_DIM / 4) + t];
        acc.x += w * v.x;
        acc.y += w * v.y;
        acc.z += w * v.z;
        acc.w += w * v.w;
    }
    *reinterpret_cast<float4*>(&pctx[(size_t)(b * N_SC + scb) * E_DIM + t * 4]) = acc;
}

// ---------------- K4: reduce context partials ----------------
__global__ __launch_bounds__(256) void k4_ctx_reduce(
    const float* __restrict__ pctx, float* __restrict__ ctx) {
    const int b = blockIdx.x;
    const int t = threadIdx.x;
    float4 acc = {0.0f, 0.0f, 0.0f, 0.0f};
#pragma unroll
    for (int s = 0; s < N_SC; ++s) {
        const float4 v = *reinterpret_cast<const float4*>(
            &pctx[(size_t)(b * N_SC + s) * E_DIM + t * 4]);
        acc.x += v.x;
        acc.y += v.y;
        acc.z += v.z;
        acc.w += v.w;
    }
    *reinterpret_cast<float4*>(&ctx[(size_t)b * E_DIM + t * 4]) = acc;
}

extern "C" void kernel_launch(void* const* d_in, const int* in_sizes, int n_in,
                              void* d_out, int out_size, void* d_ws, size_t ws_size,
                              hipStream_t stream) {
    (void)in_sizes; (void)n_in; (void)out_size; (void)ws_size;
    const float* enc = (const float*)d_in[0];
    const float* dh  = (const float*)d_in[1];
    const float* We  = (const float*)d_in[2];
    const float* be  = (const float*)d_in[3];
    const float* Wd  = (const float*)d_in[4];
    const float* bd  = (const float*)d_in[5];
    const float* vw  = (const float*)d_in[6];
    const float* vb  = (const float*)d_in[7];

    float* out = (float*)d_out;
    float* ctx_out = out;                   // [32,1024]
    float* attn_out = out + B_NUM * E_DIM;  // [32,2048]

    float* ws = (float*)d_ws;
    float* dec2    = ws;                               // 16384 floats
    float* pscores = ws + 16384;                       // 131072 floats ([M][2])
    float* pctx    = ws + 16384 + 131072;              // 524288 floats
    ushort* Wt     = (ushort*)(ws + 16384 + 131072 + 524288);  // 1MB

    k0_dec_energy<<<dim3(2, 32), 256, 0, stream>>>(dh, Wd, bd, be, dec2);
    k0b_cvt_we<<<dim3(A_DIM), 256, 0, stream>>>(We, Wt);
    k1_fused<<<dim3((M_DIM / BM4) * (A_DIM / BN4)), 256, 0, stream>>>(
        enc, Wt, dec2, vw, pscores);
    k2_softmax<<<dim3(B_NUM), 256, 0, stream>>>(pscores, vb, attn_out, 2);
    k3_ctx_partial<<<dim3(N_SC, B_NUM), 256, 0, stream>>>(enc, attn_out, pctx);
    k4_ctx_reduce<<<dim3(B_NUM), 256, 0, stream>>>(pctx, ctx_out);
}

// Round 19
// 206.436 us; speedup vs baseline: 4.4556x; 4.4556x over previous
//
#include <hip/hip_runtime.h>
#include <math.h>

#define E_DIM 1024
#define D_DIM 1024
#define A_DIM 512
#define B_NUM 32
#define S_DIM 2048
#define M_DIM (B_NUM * S_DIM)  // 65536

typedef unsigned short ushort;
typedef short short8 __attribute__((ext_vector_type(8)));
typedef float f32x4 __attribute__((ext_vector_type(4)));
typedef unsigned short ushort4v __attribute__((ext_vector_type(4)));
typedef unsigned int uint2v __attribute__((ext_vector_type(2)));

typedef const void __attribute__((address_space(1))) cglobal_t;
typedef void __attribute__((address_space(3))) lds_t;

__device__ __forceinline__ void gload_lds16(const void* g, void* l) {
    __builtin_amdgcn_global_load_lds((cglobal_t*)g, (lds_t*)l, 16, 0, 0);
}

__device__ __forceinline__ ushort f2bf(float x) {
    unsigned u = __float_as_uint(x);
    u += 0x7FFF + ((u >> 16) & 1);  // round-to-nearest-even
    return (ushort)(u >> 16);
}

__device__ __forceinline__ unsigned cvt_pk_bf16(float lo, float hi) {
    unsigned r;
    asm("v_cvt_pk_bf16_f32 %0, %1, %2" : "=v"(r) : "v"(lo), "v"(hi));
    return r;
}

__device__ __forceinline__ float fast_tanh(float x) {
    const float e = __expf(2.0f * x);
    return 1.0f - 2.0f * __builtin_amdgcn_rcpf(e + 1.0f);
}

// ---------------- K0: dec2[b][a] = dot(dh[b,:], Wd[:,a]) + bd[a] + be[a] ----------------
__global__ __launch_bounds__(256) void k0_dec_energy(
    const float* __restrict__ dh, const float* __restrict__ Wd,
    const float* __restrict__ bd, const float* __restrict__ be,
    float* __restrict__ dec2) {
    __shared__ float sdh[D_DIM];
    const int b = blockIdx.y;
    const int t = threadIdx.x;
    for (int i = t; i < D_DIM; i += 256) sdh[i] = dh[b * D_DIM + i];
    __syncthreads();
    const int a = blockIdx.x * 256 + t;
    float acc = bd[a] + be[a];
#pragma unroll 8
    for (int e = 0; e < D_DIM; ++e) acc += sdh[e] * Wd[(size_t)e * A_DIM + a];
    dec2[b * A_DIM + a] = acc;
}

// ---------------- K0b: Wt[a][e] = bf16(We[e][a]) ----------------
__global__ __launch_bounds__(256) void k0b_cvt_we(
    const float* __restrict__ We, ushort* __restrict__ Wt) {
    const int n = blockIdx.x;
    const int k0 = threadIdx.x * 4;
    ushort4v v;
#pragma unroll
    for (int j = 0; j < 4; ++j) v[j] = f2bf(We[(size_t)(k0 + j) * A_DIM + n]);
    *reinterpret_cast<ushort4v*>(&Wt[(size_t)n * E_DIM + k0]) = v;
}

// ---------------- K1: fused fp32->bf16 A-staging MFMA GEMM, coalesced A-loads ----------------
// 128x256 tile, 4 waves (64x128 each), BK=32, double-buffered 48KB LDS, 2 blocks/CU.
#define BM4 128
#define BN4 256
#define NT4 32
#define BUFU4 12288  // ushorts per buffer: A 4096 (8KB) + B 8192 (16KB)

__global__ __launch_bounds__(256, 2) void k1_fused(
    const float* __restrict__ enc, const ushort* __restrict__ Wt,
    const float* __restrict__ dec2, const float* __restrict__ v_w,
    float* __restrict__ pscores) {
    __shared__ ushort L[2 * BUFU4];  // 48KB

    const int t = threadIdx.x;
    const int l = t & 63;
    const int w = t >> 6;            // 0..3
    const int wm = w >> 1, wn = w & 1;  // 2x2 wave grid; wave-tile 64x128
    const int fr = l & 15;
    const int kg = l >> 4;

    // XCD swizzle: nwg=1024 (div 8); ny-pairs adjacent (share A-tile in L2)
    const int o = ((blockIdx.x & 7) << 7) | (blockIdx.x >> 3);
    const int x = o >> 1, ny = o & 1;
    const int row0 = x * BM4;
    const int n0 = ny * BN4;
    const int b = row0 >> 11;

    // ---- A staging: COALESCED lane map. instr q: row=q*32+(t>>3), chunk=t&7 (float4).
    const int arow = t >> 3;         // 0..31 (+ q*32)
    const int achk = t & 7;          // 16B chunk within 128B k-row
    const float* AsrcT = enc + (size_t)(row0 + arow) * E_DIM + achk * 4;
    const int aswzc = ((((achk >> 1) ^ ((t >> 4) & 3)) << 4) | ((t & 1) << 3));
    const int awbase = arow * 64 + aswzc;  // + q*2048 bytes

    // ---- B staging (pre-swizzled global source -> gload_lds, linear dest) ----
    const ushort* BsrcQ[4];
#pragma unroll
    for (int q = 0; q < 4; ++q) {
        const int row = q * 64 + w * 16 + (l >> 2);
        const int c = (l & 3) ^ ((row >> 1) & 3);
        BsrcQ[q] = Wt + (size_t)(n0 + row) * E_DIM + c * 8;
    }

    f32x4 acc[4][8];
#pragma unroll
    for (int i = 0; i < 4; ++i)
#pragma unroll
        for (int j = 0; j < 8; ++j) acc[i][j] = (f32x4){0.f, 0.f, 0.f, 0.f};

    float4 paA[4], paB[4];

#define LOADA4(pa, ktv)                                                        \
    {                                                                          \
        _Pragma("unroll") for (int q = 0; q < 4; ++q)                          \
            pa[q] = *reinterpret_cast<const float4*>(                          \
                AsrcT + (size_t)q * 32 * E_DIM + (ktv) * 32);                  \
    }

#define STAGEB4(cb, ktv)                                                       \
    {                                                                          \
        _Pragma("unroll") for (int q = 0; q < 4; ++q)                          \
            gload_lds16(BsrcQ[q] + (ktv) * 32,                                 \
                        L + (cb) * BUFU4 + 4096 + (q * 64 + w * 16) * 32);     \
    }

#define WRITEA4(cb, pa)                                                        \
    {                                                                          \
        _Pragma("unroll") for (int q = 0; q < 4; ++q) {                        \
            uint2v v2;                                                         \
            v2[0] = cvt_pk_bf16(pa[q].x, pa[q].y);                             \
            v2[1] = cvt_pk_bf16(pa[q].z, pa[q].w);                             \
            *reinterpret_cast<uint2v*>(                                        \
                (char*)L + (cb) * 24576 + q * 2048 + awbase) = v2;             \
        }                                                                      \
    }

#define MFMA_BLOCK(cur)                                                        \
    {                                                                          \
        const char* Ab = (const char*)L + (cur) * 24576;                       \
        const char* Bb = Ab + 8192;                                            \
        short8 af[4], bf[8];                                                   \
        _Pragma("unroll") for (int i = 0; i < 4; ++i) {                        \
            const int r = wm * 64 + i * 16 + fr;                               \
            af[i] = *reinterpret_cast<const short8*>(                          \
                Ab + r * 64 + ((kg ^ ((r >> 1) & 3)) << 4));                   \
        }                                                                      \
        _Pragma("unroll") for (int j = 0; j < 8; ++j) {                        \
            const int r = wn * 128 + j * 16 + fr;                              \
            bf[j] = *reinterpret_cast<const short8*>(                          \
                Bb + r * 64 + ((kg ^ ((r >> 1) & 3)) << 4));                   \
        }                                                                      \
        __builtin_amdgcn_s_setprio(1);                                         \
        _Pragma("unroll") for (int i = 0; i < 4; ++i)                          \
            _Pragma("unroll") for (int j = 0; j < 8; ++j)                      \
                acc[i][j] = __builtin_amdgcn_mfma_f32_16x16x32_bf16(           \
                    af[i], bf[j], acc[i][j], 0, 0, 0);                         \
        __builtin_amdgcn_s_setprio(0);                                         \
    }

#define WAITV(n) asm volatile("s_waitcnt vmcnt(" #n ")" ::: "memory")
#define WAITLG() asm volatile("s_waitcnt lgkmcnt(0)" ::: "memory")
#define BARRIER() __builtin_amdgcn_s_barrier()

    // ---- prologue: A(0), B(0), A(1); write A(0); wait B(0); barrier ----
    LOADA4(paA, 0);
    STAGEB4(0, 0);
    LOADA4(paB, 1);
    WAITV(8);           // A(0) regs landed
    WRITEA4(0, paA);
    WAITV(4);           // B(0) DMA landed; A(1) in flight
    WAITLG();
    BARRIER();

    // ---- main loop: steady-state 12 outstanding, counted waits, depth-2 A ----
#define ITER(kt, paW, paL)                                                     \
    {                                                                          \
        const int cur = (kt) & 1;                                              \
        STAGEB4(cur ^ 1, (kt) + 1);  /* +4: B(kt+1) */                         \
        LOADA4(paL, (kt) + 2);       /* +4: A(kt+2) */                         \
        MFMA_BLOCK(cur);                                                       \
        WAITV(8);                    /* retire A(kt+1) regs (paW) */           \
        WRITEA4(cur ^ 1, paW);                                                 \
        WAITV(4);                    /* retire B(kt+1); A(kt+2) in flight */   \
        WAITLG();                                                              \
        BARRIER();                                                             \
    }

    for (int kp = 0; kp < 30; kp += 2) {
        ITER(kp, paB, paA);      // writes A(kt+1)=paB, loads A(kt+2)->paA
        ITER(kp + 1, paA, paB);  // writes A(kt+1)=paA, loads A(kt+2)->paB
    }
    // kt = 30: stage B(31); no more A-loads; write A(31)=paB
    {
        STAGEB4(1, 31);
        MFMA_BLOCK(0);
        WAITV(4);            // retire A(31) regs (4 oldest of 8)
        WRITEA4(1, paB);
        WAITV(0);            // B(31) landed
        WAITLG();
        BARRIER();
    }
    // kt = 31: compute only
    MFMA_BLOCK(1);

    // ---- epilogue: rowsum = sum over wave's 128 cols of tanh(acc+dec2)*v_w ----
    float rowsum[4][4];
#pragma unroll
    for (int i = 0; i < 4; ++i)
#pragma unroll
        for (int r = 0; r < 4; ++r) rowsum[i][r] = 0.0f;

#pragma unroll
    for (int j = 0; j < 8; ++j) {
        const int ag = n0 + wn * 128 + j * 16 + fr;
        const float bias = dec2[b * A_DIM + ag];
        const float vw = v_w[ag];
#pragma unroll
        for (int i = 0; i < 4; ++i)
#pragma unroll
            for (int r = 0; r < 4; ++r)
                rowsum[i][r] += fast_tanh(acc[i][j][r] + bias) * vw;
    }
#pragma unroll
    for (int m = 1; m < 16; m <<= 1)
#pragma unroll
        for (int i = 0; i < 4; ++i)
#pragma unroll
            for (int r = 0; r < 4; ++r)
                rowsum[i][r] += __shfl_xor(rowsum[i][r], m, 64);

    __syncthreads();
    float* red = reinterpret_cast<float*>(L);  // [128][2]
    if (fr == 0) {
#pragma unroll
        for (int i = 0; i < 4; ++i)
#pragma unroll
            for (int r = 0; r < 4; ++r)
                red[(wm * 64 + i * 16 + kg * 4 + r) * 2 + wn] = rowsum[i][r];
    }
    __syncthreads();
    if (t < BM4)
        pscores[(size_t)(row0 + t) * 2 + ny] = red[t * 2] + red[t * 2 + 1];
}

// ---------------- K2: softmax over S per batch (W column partials) ----------------
__global__ __launch_bounds__(256) void k2_softmax(
    const float* __restrict__ pscores, const float* __restrict__ v_b,
    float* __restrict__ attn_out, int W) {
    __shared__ float sc[S_DIM];
    __shared__ float red[8];
    const int b = blockIdx.x;
    const int t = threadIdx.x;
    const int wave = t >> 6, lane = t & 63;
    const float vb = v_b[0];

    float lmax = -1e30f;
    for (int s = t; s < S_DIM; s += 256) {
        float v = vb;
        for (int c = 0; c < W; ++c) v += pscores[(size_t)(b * S_DIM + s) * W + c];
        sc[s] = v;
        lmax = fmaxf(lmax, v);
    }
#pragma unroll
    for (int off = 32; off > 0; off >>= 1) lmax = fmaxf(lmax, __shfl_down(lmax, off, 64));
    if (lane == 0) red[wave] = lmax;
    __syncthreads();
    const float bmax = fmaxf(fmaxf(red[0], red[1]), fmaxf(red[2], red[3]));

    float lsum = 0.0f;
    for (int s = t; s < S_DIM; s += 256) {
        const float e = expf(sc[s] - bmax);
        sc[s] = e;
        lsum += e;
    }
#pragma unroll
    for (int off = 32; off > 0; off >>= 1) lsum += __shfl_down(lsum, off, 64);
    if (lane == 0) red[4 + wave] = lsum;
    __syncthreads();
    const float inv = 1.0f / (red[4] + red[5] + red[6] + red[7]);
    for (int s = t; s < S_DIM; s += 256) attn_out[b * S_DIM + s] = sc[s] * inv;
}

// ---------------- K3: context partials (fp32 enc; L3-resident after K1) ----------------
#define SC_CHUNK 128
#define N_SC (S_DIM / SC_CHUNK)  // 16
__global__ __launch_bounds__(256) void k3_ctx_partial(
    const float* __restrict__ enc, const float* __restrict__ attn,
    float* __restrict__ pctx) {
    const int b = blockIdx.y;
    const int scb = blockIdx.x;
    const int t = threadIdx.x;
    const int s0 = scb * SC_CHUNK;
    float4 acc = {0.0f, 0.0f, 0.0f, 0.0f};
    const float4* encv =
        reinterpret_cast<const float4*>(enc + (size_t)(b * S_DIM + s0) * E_DIM);
#pragma unroll 4
    for (int s = 0; s < SC_CHUNK; ++s) {
        const float w = attn[b * S_DIM + s0 + s];
        const float4 v = encv[(size_t)s * (E_DIM / 4) + t];
        acc.x += w * v.x;
        acc.y += w * v.y;
        acc.z += w * v.z;
        acc.w += w * v.w;
    }
    *reinterpret_cast<float4*>(&pctx[(size_t)(b * N_SC + scb) * E_DIM + t * 4]) = acc;
}

// ---------------- K4: reduce context partials ----------------
__global__ __launch_bounds__(256) void k4_ctx_reduce(
    const float* __restrict__ pctx, float* __restrict__ ctx) {
    const int b = blockIdx.x;
    const int t = threadIdx.x;
    float4 acc = {0.0f, 0.0f, 0.0f, 0.0f};
#pragma unroll
    for (int s = 0; s < N_SC; ++s) {
        const float4 v = *reinterpret_cast<const float4*>(
            &pctx[(size_t)(b * N_SC + s) * E_DIM + t * 4]);
        acc.x += v.x;
        acc.y += v.y;
        acc.z += v.z;
        acc.w += v.w;
    }
    *reinterpret_cast<float4*>(&ctx[(size_t)b * E_DIM + t * 4]) = acc;
}

extern "C" void kernel_launch(void* const* d_in, const int* in_sizes, int n_in,
                              void* d_out, int out_size, void* d_ws, size_t ws_size,
                              hipStream_t stream) {
    (void)in_sizes; (void)n_in; (void)out_size; (void)ws_size;
    const float* enc = (const float*)d_in[0];
    const float* dh  = (const float*)d_in[1];
    const float* We  = (const float*)d_in[2];
    const float* be  = (const float*)d_in[3];
    const float* Wd  = (const float*)d_in[4];
    const float* bd  = (const float*)d_in[5];
    const float* vw  = (const float*)d_in[6];
    const float* vb  = (const float*)d_in[7];

    float* out = (float*)d_out;
    float* ctx_out = out;                   // [32,1024]
    float* attn_out = out + B_NUM * E_DIM;  // [32,2048]

    float* ws = (float*)d_ws;
    float* dec2    = ws;                               // 16384 floats
    float* pscores = ws + 16384;                       // 131072 floats ([M][2])
    float* pctx    = ws + 16384 + 131072;              // 524288 floats
    ushort* Wt     = (ushort*)(ws + 16384 + 131072 + 524288);  // 1MB

    k0_dec_energy<<<dim3(2, 32), 256, 0, stream>>>(dh, Wd, bd, be, dec2);
    k0b_cvt_we<<<dim3(A_DIM), 256, 0, stream>>>(We, Wt);
    k1_fused<<<dim3((M_DIM / BM4) * (A_DIM / BN4)), 256, 0, stream>>>(
        enc, Wt, dec2, vw, pscores);
    k2_softmax<<<dim3(B_NUM), 256, 0, stream>>>(pscores, vb, attn_out, 2);
    k3_ctx_partial<<<dim3(N_SC, B_NUM), 256, 0, stream>>>(enc, attn_out, pctx);
    k4_ctx_reduce<<<dim3(B_NUM), 256, 0, stream>>>(pctx, ctx_out);
}